// Round 1
// baseline (493.206 us; speedup 1.0000x reference)
//
#include <hip/hip_runtime.h>
#include <math.h>

#define DIN 4096
#define NH  4096

// Kernel 1: 7 GEMV slices. Wave w computes one dot product:
//   s = w/4096 in [0,7): s<3 -> Wih slice s @ x ; s>=3 -> Whh slice (s-3) @ h
// Result z[w] written to workspace. Wih slice 3 is intentionally never read
// (reference aliases Wio = Wih[2nh:3nh]).
__global__ __launch_bounds__(256) void lstm_gemv7(
    const float* __restrict__ x, const float* __restrict__ h,
    const float* __restrict__ Wih, const float* __restrict__ Whh,
    float* __restrict__ z)
{
    const int lane = threadIdx.x & 63;
    const int wave = threadIdx.x >> 6;
    const int w = blockIdx.x * 4 + wave;          // 0 .. 28671
    const int s = w >> 12;                        // slice 0..6
    const int r = w & 4095;                       // row within slice

    const float* Wrow;
    const float* v;
    if (s < 3) {
        Wrow = Wih + (size_t)s * NH * DIN + (size_t)r * DIN;
        v = x;
    } else {
        Wrow = Whh + (size_t)(s - 3) * NH * NH + (size_t)r * NH;
        v = h;
    }

    const float4* __restrict__ W4 = (const float4*)Wrow;
    const float4* __restrict__ v4 = (const float4*)v;

    float sum = 0.f;
    // 4096 floats = 1024 float4; 64 lanes -> 16 iterations, fully coalesced
    #pragma unroll
    for (int i = 0; i < 16; ++i) {
        float4 a = W4[lane + i * 64];
        float4 b = v4[lane + i * 64];
        sum += a.x * b.x + a.y * b.y + a.z * b.z + a.w * b.w;
    }

    // wave64 shuffle reduction
    #pragma unroll
    for (int off = 32; off >= 1; off >>= 1)
        sum += __shfl_down(sum, off, 64);

    if (lane == 0) z[w] = sum;
}

// Kernel 2: combine pre-activations, biases, nonlinearities; write 6 outputs
// concatenated: it, ft, gt, ot, ct, ht (each NH floats).
__global__ __launch_bounds__(256) void lstm_combine(
    const float* __restrict__ z, const float* __restrict__ c,
    const float* __restrict__ bih, const float* __restrict__ bhh,
    float* __restrict__ out)
{
    const int i = blockIdx.x * blockDim.x + threadIdx.x;
    if (i >= NH) return;

    const float zx0 = z[0 * NH + i];
    const float zx1 = z[1 * NH + i];
    const float zx2 = z[2 * NH + i];
    const float zh0 = z[3 * NH + i];
    const float zh1 = z[4 * NH + i];
    const float zh2 = z[5 * NH + i];
    const float zh3 = z[6 * NH + i];

    const float ai = zx0 + bih[0 * NH + i] + zh0 + bhh[0 * NH + i];
    const float af = zx1 + bih[1 * NH + i] + zh1 + bhh[1 * NH + i];
    const float ag = zx2 + bih[2 * NH + i] + zh2 + bhh[2 * NH + i];
    // reference bug reproduced: o-gate uses Wig@x (zx2) with slice-3 biases/Whh
    const float ao = zx2 + bih[3 * NH + i] + zh3 + bhh[3 * NH + i];

    const float it = 1.f / (1.f + expf(-ai));
    const float ft = 1.f / (1.f + expf(-af));
    const float gt = tanhf(ag);
    const float ot = 1.f / (1.f + expf(-ao));
    const float ct = ft * c[i] + it * gt;
    const float ht = ot * tanhf(ct);

    out[0 * NH + i] = it;
    out[1 * NH + i] = ft;
    out[2 * NH + i] = gt;
    out[3 * NH + i] = ot;
    out[4 * NH + i] = ct;
    out[5 * NH + i] = ht;
}

extern "C" void kernel_launch(void* const* d_in, const int* in_sizes, int n_in,
                              void* d_out, int out_size, void* d_ws, size_t ws_size,
                              hipStream_t stream) {
    const float* x   = (const float*)d_in[0];
    const float* h   = (const float*)d_in[1];
    const float* c   = (const float*)d_in[2];
    const float* Wih = (const float*)d_in[3];
    const float* Whh = (const float*)d_in[4];
    const float* bih = (const float*)d_in[5];
    const float* bhh = (const float*)d_in[6];
    float* out = (float*)d_out;
    float* z   = (float*)d_ws;   // 7 * 4096 floats = 112 KiB

    // 7 slices * 4096 rows = 28672 waves; 4 waves/block -> 7168 blocks
    lstm_gemv7<<<7168, 256, 0, stream>>>(x, h, Wih, Whh, z);
    lstm_combine<<<16, 256, 0, stream>>>(z, c, bih, bhh, out);
}

// Round 3
// 473.592 us; speedup vs baseline: 1.0414x; 1.0414x over previous
//
#include <hip/hip_runtime.h>
#include <math.h>

#define DIN 4096
#define NH  4096

typedef float f4 __attribute__((ext_vector_type(4)));

// Kernel 1: 7 GEMV slices, ONE BLOCK PER ROW (28672 blocks x 256 threads).
//   s = row/4096 in [0,7): s<3 -> Wih slice s @ x ; s>=3 -> Whh slice (s-3) @ h
// Wih slice 3 is intentionally never read (reference aliases Wio = Wih[2nh:3nh]).
// Weight rows are streamed with nontemporal loads (read-once, keep L2 for x/h).
__global__ __launch_bounds__(256) void lstm_gemv7(
    const float* __restrict__ x, const float* __restrict__ h,
    const float* __restrict__ Wih, const float* __restrict__ Whh,
    float* __restrict__ z)
{
    const int w = blockIdx.x;                     // 0 .. 28671 (row id)
    const int s = w >> 12;                        // slice 0..6
    const int r = w & 4095;                       // row within slice
    const int t = threadIdx.x;                    // 0..255
    const int lane = t & 63;
    const int wave = t >> 6;

    const float* Wrow;
    const float* v;
    if (s < 3) {
        Wrow = Wih + (size_t)s * NH * DIN + (size_t)r * DIN;
        v = x;
    } else {
        Wrow = Whh + (size_t)(s - 3) * NH * NH + (size_t)r * NH;
        v = h;
    }

    const f4* __restrict__ W4 = (const f4*)Wrow;
    const f4* __restrict__ v4 = (const f4*)v;

    // 4096 floats = 1024 float4; 256 threads -> 4 iterations, fully coalesced
    float sum = 0.f;
    #pragma unroll
    for (int i = 0; i < 4; ++i) {
        f4 a = __builtin_nontemporal_load(&W4[t + i * 256]);
        f4 b = v4[t + i * 256];
        sum += a.x * b.x + a.y * b.y + a.z * b.z + a.w * b.w;
    }

    // wave64 shuffle reduction
    #pragma unroll
    for (int off = 32; off >= 1; off >>= 1)
        sum += __shfl_down(sum, off, 64);

    __shared__ float red[4];
    if (lane == 0) red[wave] = sum;
    __syncthreads();
    if (t == 0) z[w] = red[0] + red[1] + red[2] + red[3];
}

// Kernel 2: combine pre-activations, biases, nonlinearities; write 6 outputs
// concatenated: it, ft, gt, ot, ct, ht (each NH floats).
__global__ __launch_bounds__(256) void lstm_combine(
    const float* __restrict__ z, const float* __restrict__ c,
    const float* __restrict__ bih, const float* __restrict__ bhh,
    float* __restrict__ out)
{
    const int i = blockIdx.x * blockDim.x + threadIdx.x;
    if (i >= NH) return;

    const float zx0 = z[0 * NH + i];
    const float zx1 = z[1 * NH + i];
    const float zx2 = z[2 * NH + i];
    const float zh0 = z[3 * NH + i];
    const float zh1 = z[4 * NH + i];
    const float zh2 = z[5 * NH + i];
    const float zh3 = z[6 * NH + i];

    const float ai = zx0 + bih[0 * NH + i] + zh0 + bhh[0 * NH + i];
    const float af = zx1 + bih[1 * NH + i] + zh1 + bhh[1 * NH + i];
    const float ag = zx2 + bih[2 * NH + i] + zh2 + bhh[2 * NH + i];
    // reference quirk reproduced: o-gate uses Wig@x (zx2) with slice-3 biases/Whh
    const float ao = zx2 + bih[3 * NH + i] + zh3 + bhh[3 * NH + i];

    const float it = 1.f / (1.f + expf(-ai));
    const float ft = 1.f / (1.f + expf(-af));
    const float gt = tanhf(ag);
    const float ot = 1.f / (1.f + expf(-ao));
    const float ct = ft * c[i] + it * gt;
    const float ht = ot * tanhf(ct);

    out[0 * NH + i] = it;
    out[1 * NH + i] = ft;
    out[2 * NH + i] = gt;
    out[3 * NH + i] = ot;
    out[4 * NH + i] = ct;
    out[5 * NH + i] = ht;
}

extern "C" void kernel_launch(void* const* d_in, const int* in_sizes, int n_in,
                              void* d_out, int out_size, void* d_ws, size_t ws_size,
                              hipStream_t stream) {
    const float* x   = (const float*)d_in[0];
    const float* h   = (const float*)d_in[1];
    const float* c   = (const float*)d_in[2];
    const float* Wih = (const float*)d_in[3];
    const float* Whh = (const float*)d_in[4];
    const float* bih = (const float*)d_in[5];
    const float* bhh = (const float*)d_in[6];
    float* out = (float*)d_out;
    float* z   = (float*)d_ws;   // 7 * 4096 floats = 112 KiB

    // 7 slices * 4096 rows = 28672 rows; one block per row
    lstm_gemv7<<<28672, 256, 0, stream>>>(x, h, Wih, Whh, z);
    lstm_combine<<<16, 256, 0, stream>>>(z, c, bih, bhh, out);
}